// Round 6
// baseline (217.991 us; speedup 1.0000x reference)
//
#include <hip/hip_runtime.h>
#include <math.h>

#define TL 2048
#define TD 768
#define NH 12
#define HD 64
#define NB 4
#define MTOT (NB * TL)   // 8192

typedef __bf16 bf16;
typedef __attribute__((ext_vector_type(4))) __bf16 bf16x4;
typedef __attribute__((ext_vector_type(8))) __bf16 bf16x8;
typedef __attribute__((ext_vector_type(4))) float floatx4;

// Q pre-scale: 1/sqrt(64) * log2(e)  (softmax computed in exp2 domain)
#define QSCALE 0.18033688011112042f

#define MFMA16(A, B, C) __builtin_amdgcn_mfma_f32_16x16x32_bf16(A, B, C, 0, 0, 0)

__device__ __forceinline__ void gl_lds16(const void* g, void* l) {
    __builtin_amdgcn_global_load_lds(
        (const __attribute__((address_space(1))) void*)g,
        (__attribute__((address_space(3))) void*)l, 16, 0, 0);
}

__device__ __forceinline__ floatx4 exp2x4(floatx4 a) {
    floatx4 r;
    r.x = __builtin_amdgcn_exp2f(a.x);
    r.y = __builtin_amdgcn_exp2f(a.y);
    r.z = __builtin_amdgcn_exp2f(a.z);
    r.w = __builtin_amdgcn_exp2f(a.w);
    return r;
}

// Inverse of the key->LDS-row permutation that makes QK^T's C-registers
// coincide with PV's A-fragment layout. Row r holds key kperm_inv(r).
__device__ __forceinline__ int kperm_inv(int r) {
    return (r & 35) | (((r >> 2) & 3) << 3) | (((r >> 4) & 1) << 2);
}

// ---------------------------------------------------------------------------
// Prep: blocks 0..575 transpose the 4 weight matrices to bf16 W^T;
// blocks 576.. cast x fp32->bf16. One launch instead of two.
// ---------------------------------------------------------------------------
__global__ __launch_bounds__(256)
void prep_kernel(const float* __restrict__ x,
                 const float* __restrict__ W0, const float* __restrict__ W1,
                 const float* __restrict__ W2, const float* __restrict__ W3,
                 bf16* __restrict__ xb,
                 bf16* __restrict__ T0, bf16* __restrict__ T1,
                 bf16* __restrict__ T2, bf16* __restrict__ T3)
{
    __shared__ float Ts[64][65];
    const int bid = blockIdx.x;
    const int t = threadIdx.x;
    if (bid < 576) {
        const int z = bid / 144, rem = bid % 144;
        const float* W = z == 0 ? W0 : z == 1 ? W1 : z == 2 ? W2 : W3;
        bf16*       T = z == 0 ? T0 : z == 1 ? T1 : z == 2 ? T2 : T3;
        const int k0 = (rem / 12) * 64, n0 = (rem % 12) * 64;
        const int rr = t >> 4, cc = (t & 15) * 4;
#pragma unroll
        for (int i = 0; i < 4; ++i) {
            int row = rr + i * 16;
            float4 v = *(const float4*)(W + (size_t)(k0 + row) * TD + n0 + cc);
            Ts[row][cc] = v.x; Ts[row][cc + 1] = v.y;
            Ts[row][cc + 2] = v.z; Ts[row][cc + 3] = v.w;
        }
        __syncthreads();
#pragma unroll
        for (int i = 0; i < 4; ++i) {
            int n = rr + i * 16;
            bf16x4 pk;
#pragma unroll
            for (int j = 0; j < 4; ++j) pk[j] = (bf16)Ts[cc + j][n];
            *(bf16x4*)(T + (size_t)(n0 + n) * TD + k0 + cc) = pk;
        }
    } else {
        size_t i = ((size_t)(bid - 576) * 256 + t) * 4;
        float4 v = *(const float4*)(x + i);
        bf16x4 o;
        o[0] = (bf16)v.x; o[1] = (bf16)v.y; o[2] = (bf16)v.z; o[3] = (bf16)v.w;
        *(bf16x4*)(xb + i) = o;
    }
}

// ---------------------------------------------------------------------------
// QKV GEMM: 128x128 tile, BK=64, XOR-swizzled LDS, global_load_lds staging,
// LDS-bounce coalesced epilogue.
// Q,K -> [bh][l][64] bf16 (Q pre-scaled by QSCALE); V -> [bh][d][2048] bf16.
// ---------------------------------------------------------------------------
__global__ __launch_bounds__(256)
void qkv_gemm(const bf16* __restrict__ xb,
              const bf16* __restrict__ Wqt, const bf16* __restrict__ Wkt,
              const bf16* __restrict__ Wvt,
              const float* __restrict__ bq, const float* __restrict__ bk,
              const float* __restrict__ bv,
              bf16* __restrict__ Q, bf16* __restrict__ K, bf16* __restrict__ Vt)
{
    __shared__ __align__(16) bf16 As[128 * 64];     // [row][seg^(row&7)]
    __shared__ __align__(16) bf16 Bs[128 * 64];
    __shared__ __align__(16) bf16 Eb[4][16 * 72];   // per-wave epilogue bounce

    const int t = threadIdx.x;
    const int lane = t & 63, w = t >> 6;
    const int quad = lane >> 4, l16 = lane & 15;
    const int m0 = blockIdx.x * 128;
    const int n0 = blockIdx.y * 128;
    const int which = blockIdx.z;
    const bf16*  W    = which == 0 ? Wqt : which == 1 ? Wkt : Wvt;
    const float* bias = which == 0 ? bq  : which == 1 ? bk  : bv;
    const float scale = which == 0 ? QSCALE : 1.0f;

    const int rm = (w >> 1) * 64, cn = (w & 1) * 64;

    floatx4 acc[4][4];
#pragma unroll
    for (int i = 0; i < 4; ++i)
#pragma unroll
        for (int j = 0; j < 4; ++j) acc[i][j] = (floatx4){0.f, 0.f, 0.f, 0.f};

    const bf16* gA[4];
    const bf16* gB[4];
#pragma unroll
    for (int i = 0; i < 4; ++i) {
        int n = t + i * 256, r = n >> 3, s = ((n & 7) ^ (r & 7)) * 8;
        gA[i] = xb + (size_t)(m0 + r) * TD + s;
        gB[i] = W + (size_t)(n0 + r) * TD + s;
    }

    for (int kk = 0; kk < TD; kk += 64) {
#pragma unroll
        for (int i = 0; i < 4; ++i) {
            gl_lds16(gA[i] + kk, As + t * 8 + i * 2048);
            gl_lds16(gB[i] + kk, Bs + t * 8 + i * 2048);
        }
        __syncthreads();
#pragma unroll
        for (int ks = 0; ks < 2; ++ks) {
            bf16x8 af[4], bfr[4];
#pragma unroll
            for (int mb = 0; mb < 4; ++mb) {
                int r = rm + mb * 16 + l16;
                af[mb] = *(const bf16x8*)&As[r * 64 + (((ks * 4 + quad) ^ (r & 7)) * 8)];
            }
#pragma unroll
            for (int nb = 0; nb < 4; ++nb) {
                int r = cn + nb * 16 + l16;
                bfr[nb] = *(const bf16x8*)&Bs[r * 64 + (((ks * 4 + quad) ^ (r & 7)) * 8)];
            }
#pragma unroll
            for (int mb = 0; mb < 4; ++mb)
#pragma unroll
                for (int nb = 0; nb < 4; ++nb)
                    acc[mb][nb] = MFMA16(af[mb], bfr[nb], acc[mb][nb]);
        }
        __syncthreads();
    }

    float bsc[4];
#pragma unroll
    for (int nb = 0; nb < 4; ++nb)
        bsc[nb] = bias[n0 + cn + nb * 16 + l16] * scale;

    const int token0 = m0 + rm;
    const int b  = token0 >> 11;
    const int l0 = token0 & (TL - 1);
    const int h  = (n0 + cn) >> 6;
    const int bh = b * NH + h;
    bf16* Ew = Eb[w];

    if (which < 2) {
        bf16* gp = (which == 0 ? Q : K) + ((size_t)bh * TL + l0) * HD;
#pragma unroll
        for (int mb = 0; mb < 4; ++mb) {
#pragma unroll
            for (int nb = 0; nb < 4; ++nb)
#pragma unroll
                for (int r = 0; r < 4; ++r)
                    Ew[(quad * 4 + r) * 72 + nb * 16 + l16] =
                        (bf16)(acc[mb][nb][r] * scale + bsc[nb]);
#pragma unroll
            for (int i = 0; i < 2; ++i) {
                int row = i * 8 + (lane >> 3), seg = lane & 7;
                bf16x8 v = *(const bf16x8*)&Ew[row * 72 + seg * 8];
                *(bf16x8*)(gp + (size_t)(mb * 16 + row) * HD + seg * 8) = v;
            }
        }
    } else {
#pragma unroll
        for (int nb = 0; nb < 4; ++nb) {
#pragma unroll
            for (int mb = 0; mb < 4; ++mb) {
                bf16x4 pk;
#pragma unroll
                for (int r = 0; r < 4; ++r) pk[r] = (bf16)(acc[mb][nb][r] + bsc[nb]);
                *(bf16x4*)&Ew[l16 * 72 + mb * 16 + quad * 4] = pk;
            }
#pragma unroll
            for (int i = 0; i < 2; ++i) {
                int row = i * 8 + (lane >> 3), seg = lane & 7;
                bf16x8 v = *(const bf16x8*)&Ew[row * 72 + seg * 8];
                *(bf16x8*)(Vt + ((size_t)bh * HD + nb * 16 + row) * TL + l0 + seg * 8) = v;
            }
        }
    }
}

// ---------------------------------------------------------------------------
// MFMA flash attention v6: P in registers (kperm trick), K/V staged via
// global_load_lds into DOUBLE-BUFFERED LDS with one barrier per step, so the
// next tile's fetch overlaps the current tile's compute.
// ---------------------------------------------------------------------------
__global__ __launch_bounds__(256)
void attn_kernel(const bf16* __restrict__ Q, const bf16* __restrict__ K,
                 const bf16* __restrict__ Vt, bf16* __restrict__ O)
{
    __shared__ __align__(16) bf16 Ks[2][64 * 64];   // [kperm(key)][seg^(row&7)]
    __shared__ __align__(16) bf16 Vs[2][64 * 64];   // [d][seg^(d&7)] over keys

    const int t = threadIdx.x;
    const int lane = t & 63, w = t >> 6;
    const int quad = lane >> 4, l16 = lane & 15;

    // XCD-aware swizzle: blocks on the same XCD (n%8) share one bh's K/V
    const int n = blockIdx.y * gridDim.x + blockIdx.x;   // 0..767
    const int xcd = n & 7, s = n >> 3;                   // s: 0..95
    const int bh = xcd * 6 + (s >> 4);
    const int q0 = (s & 15) * 128;

    const bf16* Qb = Q + (size_t)bh * TL * HD;
    const bf16* Kb = K + (size_t)bh * TL * HD;
    const bf16* Vb = Vt + (size_t)bh * HD * TL;

    const int qw = q0 + w * 32;
    bf16x8 qf[2][2];
#pragma unroll
    for (int mb = 0; mb < 2; ++mb)
#pragma unroll
        for (int ks = 0; ks < 2; ++ks)
            qf[mb][ks] = *(const bf16x8*)(Qb + (size_t)(qw + mb * 16 + l16) * HD
                                          + ks * 32 + quad * 8);

    float lrow[2] = {0.f, 0.f};
    floatx4 o[2][4];
#pragma unroll
    for (int mb = 0; mb < 2; ++mb)
#pragma unroll
        for (int db = 0; db < 4; ++db) o[mb][db] = (floatx4){0.f, 0.f, 0.f, 0.f};

    // staging sources: slots n = t (i=0), t+256 (i=1); row = n>>3, 8 slots/row
    const bf16* gK[2];
    const bf16* gV[2];
#pragma unroll
    for (int i = 0; i < 2; ++i) {
        int nn = t + i * 256, r = nn >> 3, sg = ((nn & 7) ^ (r & 7)) * 8;
        gK[i] = Kb + (size_t)kperm_inv(r) * HD + sg;   // + k0*HD per step
        gV[i] = Vb + (size_t)r * TL + sg;              // + k0 per step
    }

    // prefetch tile 0 into buffer 0
#pragma unroll
    for (int i = 0; i < 2; ++i) {
        gl_lds16(gK[i], Ks[0] + t * 8 + i * 2048);
        gl_lds16(gV[i], Vs[0] + t * 8 + i * 2048);
    }

    for (int kt = 0; kt < TL / 64; ++kt) {
        const int cur = kt & 1;
        __syncthreads();   // drains vmcnt: buf[cur] loaded; prev compute done
        if (kt + 1 < TL / 64) {
            const int k1 = (kt + 1) * 64;
#pragma unroll
            for (int i = 0; i < 2; ++i) {
                gl_lds16(gK[i] + (size_t)k1 * HD, Ks[cur ^ 1] + t * 8 + i * 2048);
                gl_lds16(gV[i] + k1,              Vs[cur ^ 1] + t * 8 + i * 2048);
            }
        }
        const bf16* Kc = Ks[cur];
        const bf16* Vc = Vs[cur];

        // S^T = K' Q^T : lane holds S[q=mb*16+l16][key=32(nb>>1)+4(nb&1)+8quad+r]
        floatx4 s2[2][4];
#pragma unroll
        for (int nb = 0; nb < 4; ++nb) {
            int r = nb * 16 + l16;
            bf16x8 kf0 = *(const bf16x8*)&Kc[r * 64 + ((quad ^ (r & 7)) * 8)];
            bf16x8 kf1 = *(const bf16x8*)&Kc[r * 64 + (((4 + quad) ^ (r & 7)) * 8)];
#pragma unroll
            for (int mb = 0; mb < 2; ++mb) {
                floatx4 a = (floatx4){0.f, 0.f, 0.f, 0.f};
                a = MFMA16(kf0, qf[mb][0], a);
                a = MFMA16(kf1, qf[mb][1], a);
                s2[mb][nb] = a;
            }
        }

        // P = 2^S in-register; repack into PV A-fragments (keys ks*32+8quad+j)
        bf16x8 pA[2][2];
#pragma unroll
        for (int mb = 0; mb < 2; ++mb) {
#pragma unroll
            for (int ks = 0; ks < 2; ++ks) {
                floatx4 p0 = exp2x4(s2[mb][2 * ks]);
                floatx4 p1 = exp2x4(s2[mb][2 * ks + 1]);
                lrow[mb] += (p0.x + p0.y + p0.z + p0.w) + (p1.x + p1.y + p1.z + p1.w);
                bf16x8 pk;
                pk[0] = (bf16)p0.x; pk[1] = (bf16)p0.y; pk[2] = (bf16)p0.z; pk[3] = (bf16)p0.w;
                pk[4] = (bf16)p1.x; pk[5] = (bf16)p1.y; pk[6] = (bf16)p1.z; pk[7] = (bf16)p1.w;
                pA[mb][ks] = pk;
            }
        }

        // O += P V
#pragma unroll
        for (int ks = 0; ks < 2; ++ks) {
#pragma unroll
            for (int db = 0; db < 4; ++db) {
                int r = db * 16 + l16;
                bf16x8 vf = *(const bf16x8*)&Vc[r * 64 + (((ks * 4 + quad) ^ (r & 7)) * 8)];
#pragma unroll
                for (int mb = 0; mb < 2; ++mb)
                    o[mb][db] = MFMA16(pA[mb][ks], vf, o[mb][db]);
            }
        }
    }

    // epilogue: complete row-sums (reduce over the 4 quads), normalize, store.
    const int b = bh / NH, h = bh % NH;
#pragma unroll
    for (int mb = 0; mb < 2; ++mb) {
        lrow[mb] += __shfl_xor(lrow[mb], 16);
        lrow[mb] += __shfl_xor(lrow[mb], 32);
        floatx4 inv;
#pragma unroll
        for (int r = 0; r < 4; ++r)
            inv[r] = 1.0f / __shfl(lrow[mb], (lane & 48) | (quad * 4 + r));
#pragma unroll
        for (int db = 0; db < 4; ++db)
#pragma unroll
            for (int r = 0; r < 4; ++r) {
                int l = qw + mb * 16 + quad * 4 + r;
                O[((size_t)b * TL + l) * TD + h * HD + db * 16 + l16] =
                    (bf16)(o[mb][db][r] * inv[r]);
            }
    }
}

// ---------------------------------------------------------------------------
// Output projection: out fp32 = O_bf16 @ Wo + bo. BK=64, XOR swizzle,
// LDS-bounce epilogue.
// ---------------------------------------------------------------------------
__global__ __launch_bounds__(256)
void oproj_gemm(const bf16* __restrict__ A, const bf16* __restrict__ Wt,
                const float* __restrict__ bo, float* __restrict__ out)
{
    __shared__ __align__(16) bf16 As[128 * 64];
    __shared__ __align__(16) bf16 Bs[128 * 64];
    __shared__ __align__(16) float Ef[4][16 * 68];   // per-wave f32 bounce

    const int t = threadIdx.x;
    const int lane = t & 63, w = t >> 6;
    const int quad = lane >> 4, l16 = lane & 15;
    const int m0 = blockIdx.x * 128;
    const int n0 = blockIdx.y * 128;
    const int rm = (w >> 1) * 64, cn = (w & 1) * 64;

    floatx4 acc[4][4];
#pragma unroll
    for (int i = 0; i < 4; ++i)
#pragma unroll
        for (int j = 0; j < 4; ++j) acc[i][j] = (floatx4){0.f, 0.f, 0.f, 0.f};

    const bf16* gA[4];
    const bf16* gB[4];
#pragma unroll
    for (int i = 0; i < 4; ++i) {
        int n = t + i * 256, r = n >> 3, s = ((n & 7) ^ (r & 7)) * 8;
        gA[i] = A + (size_t)(m0 + r) * TD + s;
        gB[i] = Wt + (size_t)(n0 + r) * TD + s;
    }

    for (int kk = 0; kk < TD; kk += 64) {
#pragma unroll
        for (int i = 0; i < 4; ++i) {
            gl_lds16(gA[i] + kk, As + t * 8 + i * 2048);
            gl_lds16(gB[i] + kk, Bs + t * 8 + i * 2048);
        }
        __syncthreads();
#pragma unroll
        for (int ks = 0; ks < 2; ++ks) {
            bf16x8 af[4], bfr[4];
#pragma unroll
            for (int mb = 0; mb < 4; ++mb) {
                int r = rm + mb * 16 + l16;
                af[mb] = *(const bf16x8*)&As[r * 64 + (((ks * 4 + quad) ^ (r & 7)) * 8)];
            }
#pragma unroll
            for (int nb = 0; nb < 4; ++nb) {
                int r = cn + nb * 16 + l16;
                bfr[nb] = *(const bf16x8*)&Bs[r * 64 + (((ks * 4 + quad) ^ (r & 7)) * 8)];
            }
#pragma unroll
            for (int mb = 0; mb < 4; ++mb)
#pragma unroll
                for (int nb = 0; nb < 4; ++nb)
                    acc[mb][nb] = MFMA16(af[mb], bfr[nb], acc[mb][nb]);
        }
        __syncthreads();
    }

    float bb[4];
#pragma unroll
    for (int nb = 0; nb < 4; ++nb) bb[nb] = bo[n0 + cn + nb * 16 + l16];

    float* Ew = Ef[w];
#pragma unroll
    for (int mb = 0; mb < 4; ++mb) {
#pragma unroll
        for (int nb = 0; nb < 4; ++nb)
#pragma unroll
            for (int r = 0; r < 4; ++r)
                Ew[(quad * 4 + r) * 68 + nb * 16 + l16] = acc[mb][nb][r] + bb[nb];
#pragma unroll
        for (int i = 0; i < 4; ++i) {
            int row = i * 4 + (lane >> 4), seg = lane & 15;
            float4 v = *(const float4*)&Ew[row * 68 + seg * 4];
            *(float4*)(out + (size_t)(m0 + rm + mb * 16 + row) * TD + n0 + cn + seg * 4) = v;
        }
    }
}

// ---------------------------------------------------------------------------
extern "C" void kernel_launch(void* const* d_in, const int* in_sizes, int n_in,
                              void* d_out, int out_size, void* d_ws, size_t ws_size,
                              hipStream_t stream)
{
    const float* x  = (const float*)d_in[0];
    const float* Wq = (const float*)d_in[1];
    const float* bq = (const float*)d_in[2];
    const float* Wk = (const float*)d_in[3];
    const float* bk = (const float*)d_in[4];
    const float* Wv = (const float*)d_in[5];
    const float* bv = (const float*)d_in[6];
    const float* Wo = (const float*)d_in[7];
    const float* bo = (const float*)d_in[8];

    const size_t NXE = (size_t)MTOT * TD;    // 6,291,456
    const size_t NWE = (size_t)TD * TD;      // 589,824

    bf16* xb  = (bf16*)d_ws;
    bf16* Wqt = xb + NXE;
    bf16* Wkt = Wqt + NWE;
    bf16* Wvt = Wkt + NWE;
    bf16* Wot = Wvt + NWE;
    bf16* Qb  = Wot + NWE;
    bf16* Kb  = Qb + NXE;
    bf16* Vtb = Kb + NXE;
    bf16* Ob  = Vtb + NXE;

    prep_kernel<<<576 + 6144, 256, 0, stream>>>(x, Wq, Wk, Wv, Wo,
                                                xb, Wqt, Wkt, Wvt, Wot);
    qkv_gemm<<<dim3(MTOT / 128, TD / 128, 3), 256, 0, stream>>>(
        xb, Wqt, Wkt, Wvt, bq, bk, bv, Qb, Kb, Vtb);
    attn_kernel<<<dim3(TL / 128, NB * NH), 256, 0, stream>>>(Qb, Kb, Vtb, Ob);
    oproj_gemm<<<dim3(MTOT / 128, TD / 128), 256, 0, stream>>>(Ob, Wot, bo,
                                                               (float*)d_out);
}